// Round 11
// baseline (1264.013 us; speedup 1.0000x reference)
//
#include <hip/hip_runtime.h>
#include <stdint.h>

#define DIM  2048
#define NEXP 8
#define NH   1408
#define NHS  2816
#define NT   8192
#define NA   (NT*2)
#define NV   (NEXP*2)   // virtual segments: (expert, rank)

typedef unsigned short u16;
typedef short bf16x8 __attribute__((ext_vector_type(8)));
typedef float f32x4 __attribute__((ext_vector_type(4)));

typedef __attribute__((address_space(1))) const uint32_t gas_u32;
typedef __attribute__((address_space(3))) uint32_t las_u32;

__device__ __forceinline__ u16 f2bf(float f) {
  uint32_t x = __builtin_bit_cast(uint32_t, f);
  x += 0x7FFFu + ((x >> 16) & 1u);
  return (u16)(x >> 16);
}

__device__ __forceinline__ void gload_lds16(const void* g, void* l) {
  __builtin_amdgcn_global_load_lds((gas_u32*)g, (las_u32*)l, 16, 0, 0);
}

// XCD-aware contiguous-band remap (round-9 proven: FETCH -42%).
__device__ __forceinline__ bool xcd_map_band(int G, int& nt, int& mt) {
  const int gx = gridDim.x;
  int f = blockIdx.y * gx + blockIdx.x;
  int xcd = f & 7;
  int local = f >> 3;
  if (G <= 0) return false;
  int band = (G + 7) >> 3;
  int slot = local % band;
  int ntv  = local / band;
  if (ntv >= gx) return false;
  int mtv = xcd * band + slot;
  if (mtv >= G) return false;
  nt = ntv; mt = mtv;
  return true;
}

struct alignas(16) US8 { u16 u[8]; };
struct alignas(8)  US4 { u16 u[4]; };

// ---------------- fp32 -> bf16 conversion (weights) ----------------
__global__ __launch_bounds__(256) void convert_kernel(const float* __restrict__ src,
                                                      u16* __restrict__ dst, int n8) {
  int i = blockIdx.x * 256 + threadIdx.x;
  if (i >= n8) return;
  const float4* s = (const float4*)src + (size_t)i * 2;
  float4 a = s[0], b = s[1];
  US8 r;
  r.u[0]=f2bf(a.x); r.u[1]=f2bf(a.y); r.u[2]=f2bf(a.z); r.u[3]=f2bf(a.w);
  r.u[4]=f2bf(b.x); r.u[5]=f2bf(b.y); r.u[6]=f2bf(b.z); r.u[7]=f2bf(b.w);
  *((US8*)dst + i) = r;
}

// ---------------- router (fused: also emits x as bf16) ----------------
__global__ void zero_counts(int* counts) { if (threadIdx.x < NV) counts[threadIdx.x] = 0; }

__global__ __launch_bounds__(64) void router_kernel(const float* __restrict__ x,
    const float* __restrict__ gw, const float* __restrict__ gb,
    u16* __restrict__ xb,
    int* __restrict__ tope, float* __restrict__ topw, int* __restrict__ counts) {
  const int t = blockIdx.x;
  const int lane = threadIdx.x;
  const float4* xr = (const float4*)(x + (size_t)t * DIM);
  float4 xv[8];
  #pragma unroll
  for (int j = 0; j < 8; j++) xv[j] = xr[j * 64 + lane];
  US4* xrow = (US4*)(xb + (size_t)t * DIM);
  #pragma unroll
  for (int j = 0; j < 8; j++) {
    US4 r4;
    r4.u[0] = f2bf(xv[j].x); r4.u[1] = f2bf(xv[j].y);
    r4.u[2] = f2bf(xv[j].z); r4.u[3] = f2bf(xv[j].w);
    xrow[j * 64 + lane] = r4;
  }
  float p[NEXP];
  #pragma unroll
  for (int e = 0; e < NEXP; e++) {
    const float4* gr = (const float4*)(gw + (size_t)e * DIM);
    float s = 0.f;
    #pragma unroll
    for (int j = 0; j < 8; j++) {
      float4 g = gr[j * 64 + lane];
      s += xv[j].x*g.x + xv[j].y*g.y + xv[j].z*g.z + xv[j].w*g.w;
    }
    p[e] = s;
  }
  #pragma unroll
  for (int off = 32; off > 0; off >>= 1) {
    #pragma unroll
    for (int e = 0; e < NEXP; e++) p[e] += __shfl_xor(p[e], off);
  }
  if (lane == 0) {
    float pr[NEXP];
    float mx = -1e30f;
    #pragma unroll
    for (int e = 0; e < NEXP; e++) { p[e] += gb[e]; mx = fmaxf(mx, p[e]); }
    float den = 0.f;
    #pragma unroll
    for (int e = 0; e < NEXP; e++) { pr[e] = __expf(p[e] - mx); den += pr[e]; }
    float inv = 1.f / den;
    #pragma unroll
    for (int e = 0; e < NEXP; e++) pr[e] *= inv;
    int e0 = 0;
    #pragma unroll
    for (int e = 1; e < NEXP; e++) if (pr[e] > pr[e0]) e0 = e;
    int e1 = (e0 == 0) ? 1 : 0;
    #pragma unroll
    for (int e = 0; e < NEXP; e++) { if (e != e0 && pr[e] > pr[e1]) e1 = e; }
    tope[t*2]   = e0; tope[t*2+1] = e1;
    topw[t*2]   = pr[e0]; topw[t*2+1] = pr[e1];
    atomicAdd(&counts[e0*2+0], 1); atomicAdd(&counts[e1*2+1], 1);
  }
}

__global__ void scan_kernel(const int* __restrict__ counts, int* __restrict__ offsets,
                            int* __restrict__ cursor) {
  if (threadIdx.x == 0) {
    int s = 0;
    for (int v = 0; v < NV; v++) { offsets[v] = s; cursor[v] = s; s += counts[v]; }
    offsets[NV] = s;
  }
}

__global__ __launch_bounds__(256) void assign_kernel(const int* __restrict__ tope,
    const float* __restrict__ topw, int* __restrict__ cursor,
    int* __restrict__ ptok, float* __restrict__ pw) {
  int t = blockIdx.x * 256 + threadIdx.x;
  if (t >= NT) return;
  #pragma unroll
  for (int k = 0; k < 2; k++) {
    int v = tope[t*2+k] * 2 + k;     // (expert, rank) virtual segment
    int pos = atomicAdd(&cursor[v], 1);
    ptok[pos] = t;
    pw[pos]   = topw[t*2+k];
  }
}

// ---------------- fused up-projection (gate & up), SwiGLU epilogue ----------------
// C tile: 128 rows x 64 cols of BOTH matrices. BK=64. (round-3/9 proven)
// ROUTED: blockIdx.z = virtual segment v in [0,16); weights use e = v>>1.
template<bool ROUTED>
__global__ __launch_bounds__(256, 2) void gemm_up(
    const u16* __restrict__ X, const u16* __restrict__ Wg, const u16* __restrict__ Wu,
    const float* __restrict__ Bg, const float* __restrict__ Bu,
    u16* __restrict__ Hout,
    const int* __restrict__ offsets, const int* __restrict__ ptok,
    const float* __restrict__ pw, int Nfeat)
{
  int e = 0, seg = 0, cnt = NT;
  if (ROUTED) {
    int v = blockIdx.z;
    e = v >> 1;
    seg = offsets[v];
    cnt = offsets[v+1] - seg;
  }
  const int G = ROUTED ? ((cnt + 127) >> 7) : (int)gridDim.y;
  int nt, mt;
  if (!xcd_map_band(G, nt, mt)) return;
  const int m0 = mt * 128;
  const int tid = threadIdx.x;
  const int wave = tid >> 6, lane = tid & 63;

  __shared__ u16 sA[128*64];
  __shared__ u16 sBg[64*64];
  __shared__ u16 sBu[64*64];
  char* sAc  = (char*)sA;
  char* sBgc = (char*)sBg;
  char* sBuc = (char*)sBu;

  const u16* aSrc[4];
  #pragma unroll
  for (int j = 0; j < 4; j++) {
    int c = j * 256 + tid;
    int row = c >> 3, gch = (c & 7) ^ (row & 7);
    int r = m0 + row;
    size_t srow;
    if (ROUTED) { r = (r < cnt) ? r : (cnt - 1); srow = (size_t)ptok[seg + r]; }
    else        { srow = (size_t)r; }
    aSrc[j] = X + srow * DIM + gch * 8;
  }
  const size_t wOff = ROUTED ? (size_t)e * Nfeat * DIM : 0;
  const u16 *bgSrc[2], *buSrc[2];
  #pragma unroll
  for (int j = 0; j < 2; j++) {
    int c = j * 256 + tid;
    int row = c >> 3, gch = (c & 7) ^ (row & 7);
    bgSrc[j] = Wg + wOff + (size_t)(nt * 64 + row) * DIM + gch * 8;
    buSrc[j] = Wu + wOff + (size_t)(nt * 64 + row) * DIM + gch * 8;
  }

  f32x4 accg[4][2], accu[4][2];
  #pragma unroll
  for (int m = 0; m < 4; m++)
    #pragma unroll
    for (int n = 0; n < 2; n++) { accg[m][n] = (f32x4){0,0,0,0}; accu[m][n] = (f32x4){0,0,0,0}; }

  const int wr = (wave >> 1) * 64;
  const int wc = (wave & 1) * 32;
  const int lr = lane & 15, kg = lane >> 4;
  int aOff[4], bOff[2];
  #pragma unroll
  for (int m = 0; m < 4; m++) { int row = wr + m*16 + lr; aOff[m] = row*128 + ((kg ^ (row & 7)) & 7) * 16; }
  #pragma unroll
  for (int n = 0; n < 2; n++) { int row = wc + n*16 + lr; bOff[n] = row*128 + ((kg ^ (row & 7)) & 7) * 16; }

  for (int k0 = 0; k0 < DIM; k0 += 64) {
    __syncthreads();
    #pragma unroll
    for (int j = 0; j < 4; j++) gload_lds16(aSrc[j] + k0, sAc + j*4096 + wave*1024);
    #pragma unroll
    for (int j = 0; j < 2; j++) {
      gload_lds16(bgSrc[j] + k0, sBgc + j*4096 + wave*1024);
      gload_lds16(buSrc[j] + k0, sBuc + j*4096 + wave*1024);
    }
    __syncthreads();
    bf16x8 af[4][2], bgf[2][2], buf2[2][2];
    #pragma unroll
    for (int m = 0; m < 4; m++) {
      af[m][0] = *(const bf16x8*)(sAc + aOff[m]);
      af[m][1] = *(const bf16x8*)(sAc + (aOff[m] ^ 64));
    }
    #pragma unroll
    for (int n = 0; n < 2; n++) {
      bgf[n][0]  = *(const bf16x8*)(sBgc + bOff[n]);
      bgf[n][1]  = *(const bf16x8*)(sBgc + (bOff[n] ^ 64));
      buf2[n][0] = *(const bf16x8*)(sBuc + bOff[n]);
      buf2[n][1] = *(const bf16x8*)(sBuc + (bOff[n] ^ 64));
    }
    #pragma unroll
    for (int kk = 0; kk < 2; kk++)
      #pragma unroll
      for (int m = 0; m < 4; m++)
        #pragma unroll
        for (int n = 0; n < 2; n++) {
          accg[m][n] = __builtin_amdgcn_mfma_f32_16x16x32_bf16(af[m][kk], bgf[n][kk],  accg[m][n], 0, 0, 0);
          accu[m][n] = __builtin_amdgcn_mfma_f32_16x16x32_bf16(af[m][kk], buf2[n][kk], accu[m][n], 0, 0, 0);
        }
  }

  const int col0 = nt * 64 + wc;
  #pragma unroll
  for (int m = 0; m < 4; m++) {
    #pragma unroll
    for (int n = 0; n < 2; n++) {
      #pragma unroll
      for (int i = 0; i < 4; i++) {
        int rl = wr + m*16 + (lane >> 4) * 4 + i;
        int gr = m0 + rl;
        if (ROUTED && gr >= cnt) continue;
        int col = col0 + n*16 + (lane & 15);
        float g = accg[m][n][i];
        float u = accu[m][n][i];
        float scale = 1.f;
        size_t orow;
        if (ROUTED) {
          int ai = seg + gr;
          scale = pw[ai];
          g += Bg[e * Nfeat + col];
          u += Bu[e * Nfeat + col];
          orow = (size_t)ai;
        } else {
          orow = (size_t)gr;
        }
        float s = g / (1.f + __expf(-g));
        Hout[orow * (size_t)Nfeat + col] = f2bf(s * u * scale);
      }
    }
  }
}

// ---------------- down-projection ----------------
// C tile: 128 x 128. BK=64.
// ROUTED: processes rank-class KPAR segments (v = 2*blockIdx.z + KPAR); each
// token appears at most once per rank-class -> plain RMW into out, NO atomics.
template<bool ROUTED>
__global__ __launch_bounds__(256, 2) void gemm_down(
    const u16* __restrict__ Hin, const u16* __restrict__ W,
    const float* __restrict__ B2, float* __restrict__ Out,
    const int* __restrict__ offsets, const int* __restrict__ ptok,
    const float* __restrict__ pw, int Kdim, int kpar)
{
  int e = 0, seg = 0, cnt = NT;
  if (ROUTED) {
    e = blockIdx.z;
    int v = e * 2 + kpar;
    seg = offsets[v];
    cnt = offsets[v+1] - seg;
  }
  const int G = ROUTED ? ((cnt + 127) >> 7) : (int)gridDim.y;
  int nt, mt;
  if (!xcd_map_band(G, nt, mt)) return;
  const int m0 = mt * 128;
  const int tid = threadIdx.x;
  const int wave = tid >> 6, lane = tid & 63;

  __shared__ u16 sA[128*64];
  __shared__ u16 sB[128*64];
  char* sAc = (char*)sA;
  char* sBc = (char*)sB;

  const u16* aSrc[4]; const u16* bSrc[4];
  #pragma unroll
  for (int j = 0; j < 4; j++) {
    int c = j * 256 + tid;
    int row = c >> 3, gch = (c & 7) ^ (row & 7);
    int r = m0 + row;
    size_t arow;
    if (ROUTED) { r = (r < cnt) ? r : (cnt - 1); arow = (size_t)(seg + r); }
    else        { arow = (size_t)r; }
    aSrc[j] = Hin + arow * (size_t)Kdim + gch * 8;
    size_t brow = (size_t)(ROUTED ? e * DIM : 0) + nt * 128 + row;
    bSrc[j] = W + brow * (size_t)Kdim + gch * 8;
  }

  f32x4 acc[4][4];
  #pragma unroll
  for (int m = 0; m < 4; m++)
    #pragma unroll
    for (int n = 0; n < 4; n++) acc[m][n] = (f32x4){0,0,0,0};

  const int wr = (wave >> 1) * 64, wc = (wave & 1) * 64;
  const int lr = lane & 15, kg = lane >> 4;
  int aOff[4], bOff[4];
  #pragma unroll
  for (int m = 0; m < 4; m++) { int row = wr + m*16 + lr; aOff[m] = row*128 + ((kg ^ (row & 7)) & 7) * 16; }
  #pragma unroll
  for (int n = 0; n < 4; n++) { int row = wc + n*16 + lr; bOff[n] = row*128 + ((kg ^ (row & 7)) & 7) * 16; }

  for (int k0 = 0; k0 < Kdim; k0 += 64) {
    __syncthreads();
    #pragma unroll
    for (int j = 0; j < 4; j++) {
      gload_lds16(aSrc[j] + k0, sAc + j*4096 + wave*1024);
      gload_lds16(bSrc[j] + k0, sBc + j*4096 + wave*1024);
    }
    __syncthreads();
    bf16x8 af[4][2], bf[4][2];
    #pragma unroll
    for (int m = 0; m < 4; m++) {
      af[m][0] = *(const bf16x8*)(sAc + aOff[m]);
      af[m][1] = *(const bf16x8*)(sAc + (aOff[m] ^ 64));
    }
    #pragma unroll
    for (int n = 0; n < 4; n++) {
      bf[n][0] = *(const bf16x8*)(sBc + bOff[n]);
      bf[n][1] = *(const bf16x8*)(sBc + (bOff[n] ^ 64));
    }
    #pragma unroll
    for (int kk = 0; kk < 2; kk++)
      #pragma unroll
      for (int m = 0; m < 4; m++)
        #pragma unroll
        for (int n = 0; n < 4; n++)
          acc[m][n] = __builtin_amdgcn_mfma_f32_16x16x32_bf16(af[m][kk], bf[n][kk], acc[m][n], 0, 0, 0);
  }

  const int col0 = nt * 128 + wc;
  #pragma unroll
  for (int m = 0; m < 4; m++) {
    #pragma unroll
    for (int n = 0; n < 4; n++) {
      #pragma unroll
      for (int i = 0; i < 4; i++) {
        int rl = wr + m*16 + (lane >> 4) * 4 + i;
        int gr = m0 + rl;
        int col = col0 + n*16 + (lane & 15);
        float v = acc[m][n][i];
        if (ROUTED) {
          if (gr < cnt) {
            int ai = seg + gr;
            int token = ptok[ai];
            float w = pw[ai];
            float* p = Out + (size_t)token * DIM + col;
            *p = *p + v + w * B2[e * DIM + col];   // unique token/pass: no atomic
          }
        } else {
          Out[(size_t)gr * DIM + col] = v;
        }
      }
    }
  }
}

// ---------------- launch ----------------
extern "C" void kernel_launch(void* const* d_in, const int* in_sizes, int n_in,
                              void* d_out, int out_size, void* d_ws, size_t ws_size,
                              hipStream_t stream) {
  (void)in_sizes; (void)n_in; (void)out_size; (void)ws_size;
  const float* x      = (const float*)d_in[0];
  const float* gate_w = (const float*)d_in[1];
  const float* gate_b = (const float*)d_in[2];
  const float* w1     = (const float*)d_in[3];
  const float* b1     = (const float*)d_in[4];
  const float* w3     = (const float*)d_in[5];
  const float* b3     = (const float*)d_in[6];
  const float* w2     = (const float*)d_in[7];
  const float* b2     = (const float*)d_in[8];
  const float* shg    = (const float*)d_in[9];
  const float* shu    = (const float*)d_in[10];
  const float* shd    = (const float*)d_in[11];
  float* out = (float*)d_out;

  char* ws = (char*)d_ws;
  size_t off = 0;
  auto alloc = [&](size_t bytes) -> void* {
    void* p = ws + off;
    off += (bytes + 255) & ~(size_t)255;
    return p;
  };
  u16* xb    = (u16*)alloc((size_t)NT * DIM * 2);
  u16* w1b   = (u16*)alloc((size_t)NEXP * NH * DIM * 2);
  u16* w3b   = (u16*)alloc((size_t)NEXP * NH * DIM * 2);
  u16* w2b   = (u16*)alloc((size_t)NEXP * DIM * NH * 2);
  u16* shgb  = (u16*)alloc((size_t)NHS * DIM * 2);
  u16* shub  = (u16*)alloc((size_t)NHS * DIM * 2);
  u16* shdb  = (u16*)alloc((size_t)DIM * NHS * 2);
  u16* hsh   = (u16*)alloc((size_t)NT * NHS * 2);
  u16* hr    = (u16*)alloc((size_t)NA * NH * 2);
  int*   tope    = (int*)alloc(NT * 2 * 4);
  float* topw    = (float*)alloc(NT * 2 * 4);
  int*   ptok    = (int*)alloc(NA * 4);
  float* pw      = (float*)alloc(NA * 4);
  int*   counts  = (int*)alloc(256);
  int*   offsets = (int*)alloc(256);
  int*   cursor  = (int*)alloc(256);

  auto cvt = [&](const float* s, u16* d, size_t n) {
    int n8 = (int)(n / 8);
    convert_kernel<<<(n8 + 255) / 256, 256, 0, stream>>>(s, d, n8);
  };
  cvt(w1,  w1b,  (size_t)NEXP * NH * DIM);
  cvt(w3,  w3b,  (size_t)NEXP * NH * DIM);
  cvt(w2,  w2b,  (size_t)NEXP * DIM * NH);
  cvt(shg, shgb, (size_t)NHS * DIM);
  cvt(shu, shub, (size_t)NHS * DIM);
  cvt(shd, shdb, (size_t)DIM * NHS);

  zero_counts<<<1, 64, 0, stream>>>(counts);
  router_kernel<<<NT, 64, 0, stream>>>(x, gate_w, gate_b, xb, tope, topw, counts);
  scan_kernel<<<1, 1, 0, stream>>>(counts, offsets, cursor);
  assign_kernel<<<NT / 256, 256, 0, stream>>>(tope, topw, cursor, ptok, pw);

  // shared expert: up (fused SwiGLU) then down (plain store initializes out)
  gemm_up<false><<<dim3(NHS / 64, NT / 128, 1), 256, 0, stream>>>(
      xb, shgb, shub, nullptr, nullptr, hsh, nullptr, nullptr, nullptr, NHS);
  // routed experts: up over 16 virtual (expert, rank) segments
  gemm_up<true><<<dim3(NH / 64, NT / 128, NV), 256, 0, stream>>>(
      xb, w1b, w3b, b1, b3, hr, offsets, ptok, pw, NH);
  // shared down -> out (full overwrite)
  gemm_down<false><<<dim3(DIM / 128, NT / 128, 1), 256, 0, stream>>>(
      hsh, shdb, nullptr, out, nullptr, nullptr, nullptr, NHS, 0);
  // routed down: two rank-class passes, plain RMW (tokens unique per pass)
  gemm_down<true><<<dim3(DIM / 128, NT / 128, NEXP), 256, 0, stream>>>(
      hr, w2b, b2, out, offsets, ptok, pw, NH, 0);
  gemm_down<true><<<dim3(DIM / 128, NT / 128, NEXP), 256, 0, stream>>>(
      hr, w2b, b2, out, offsets, ptok, pw, NH, 1);
}

// Round 12
// 1112.171 us; speedup vs baseline: 1.1365x; 1.1365x over previous
//
#include <hip/hip_runtime.h>
#include <stdint.h>

#define DIM  2048
#define NEXP 8
#define NH   1408
#define NHS  2816
#define NT   8192
#define NA   (NT*2)

typedef unsigned short u16;
typedef short bf16x8 __attribute__((ext_vector_type(8)));
typedef float f32x4 __attribute__((ext_vector_type(4)));

typedef __attribute__((address_space(1))) const uint32_t gas_u32;
typedef __attribute__((address_space(3))) uint32_t las_u32;

__device__ __forceinline__ u16 f2bf(float f) {
  uint32_t x = __builtin_bit_cast(uint32_t, f);
  x += 0x7FFFu + ((x >> 16) & 1u);
  return (u16)(x >> 16);
}

__device__ __forceinline__ void gload_lds16(const void* g, void* l) {
  __builtin_amdgcn_global_load_lds((gas_u32*)g, (las_u32*)l, 16, 0, 0);
}

// XCD-aware contiguous-band remap (round-9 proven: FETCH -42%, +17 us net).
__device__ __forceinline__ bool xcd_map_band(int G, int& nt, int& mt) {
  const int gx = gridDim.x;
  int f = blockIdx.y * gx + blockIdx.x;
  int xcd = f & 7;
  int local = f >> 3;
  if (G <= 0) return false;
  int band = (G + 7) >> 3;
  int slot = local % band;
  int ntv  = local / band;
  if (ntv >= gx) return false;
  int mtv = xcd * band + slot;
  if (mtv >= G) return false;
  nt = ntv; mt = mtv;
  return true;
}

struct alignas(16) US8 { u16 u[8]; };
struct alignas(8)  US4 { u16 u[4]; };

// ---------------- fp32 -> bf16 conversion (weights) ----------------
__global__ __launch_bounds__(256) void convert_kernel(const float* __restrict__ src,
                                                      u16* __restrict__ dst, int n8) {
  int i = blockIdx.x * 256 + threadIdx.x;
  if (i >= n8) return;
  const float4* s = (const float4*)src + (size_t)i * 2;
  float4 a = s[0], b = s[1];
  US8 r;
  r.u[0]=f2bf(a.x); r.u[1]=f2bf(a.y); r.u[2]=f2bf(a.z); r.u[3]=f2bf(a.w);
  r.u[4]=f2bf(b.x); r.u[5]=f2bf(b.y); r.u[6]=f2bf(b.z); r.u[7]=f2bf(b.w);
  *((US8*)dst + i) = r;
}

// ---------------- router (fused: also emits x as bf16) ----------------
__global__ void zero_counts(int* counts) { if (threadIdx.x < NEXP) counts[threadIdx.x] = 0; }

__global__ __launch_bounds__(64) void router_kernel(const float* __restrict__ x,
    const float* __restrict__ gw, const float* __restrict__ gb,
    u16* __restrict__ xb,
    int* __restrict__ tope, float* __restrict__ topw, int* __restrict__ counts) {
  const int t = blockIdx.x;
  const int lane = threadIdx.x;
  const float4* xr = (const float4*)(x + (size_t)t * DIM);
  float4 xv[8];
  #pragma unroll
  for (int j = 0; j < 8; j++) xv[j] = xr[j * 64 + lane];
  US4* xrow = (US4*)(xb + (size_t)t * DIM);
  #pragma unroll
  for (int j = 0; j < 8; j++) {
    US4 r4;
    r4.u[0] = f2bf(xv[j].x); r4.u[1] = f2bf(xv[j].y);
    r4.u[2] = f2bf(xv[j].z); r4.u[3] = f2bf(xv[j].w);
    xrow[j * 64 + lane] = r4;
  }
  float p[NEXP];
  #pragma unroll
  for (int e = 0; e < NEXP; e++) {
    const float4* gr = (const float4*)(gw + (size_t)e * DIM);
    float s = 0.f;
    #pragma unroll
    for (int j = 0; j < 8; j++) {
      float4 g = gr[j * 64 + lane];
      s += xv[j].x*g.x + xv[j].y*g.y + xv[j].z*g.z + xv[j].w*g.w;
    }
    p[e] = s;
  }
  #pragma unroll
  for (int off = 32; off > 0; off >>= 1) {
    #pragma unroll
    for (int e = 0; e < NEXP; e++) p[e] += __shfl_xor(p[e], off);
  }
  if (lane == 0) {
    float pr[NEXP];
    float mx = -1e30f;
    #pragma unroll
    for (int e = 0; e < NEXP; e++) { p[e] += gb[e]; mx = fmaxf(mx, p[e]); }
    float den = 0.f;
    #pragma unroll
    for (int e = 0; e < NEXP; e++) { pr[e] = __expf(p[e] - mx); den += pr[e]; }
    float inv = 1.f / den;
    #pragma unroll
    for (int e = 0; e < NEXP; e++) pr[e] *= inv;
    int e0 = 0;
    #pragma unroll
    for (int e = 1; e < NEXP; e++) if (pr[e] > pr[e0]) e0 = e;
    int e1 = (e0 == 0) ? 1 : 0;
    #pragma unroll
    for (int e = 0; e < NEXP; e++) { if (e != e0 && pr[e] > pr[e1]) e1 = e; }
    tope[t*2]   = e0; tope[t*2+1] = e1;
    topw[t*2]   = pr[e0]; topw[t*2+1] = pr[e1];
    atomicAdd(&counts[e0], 1); atomicAdd(&counts[e1], 1);
  }
}

__global__ void scan_kernel(const int* __restrict__ counts, int* __restrict__ offsets,
                            int* __restrict__ cursor) {
  if (threadIdx.x == 0) {
    int s = 0;
    for (int e = 0; e < NEXP; e++) { offsets[e] = s; cursor[e] = s; s += counts[e]; }
    offsets[NEXP] = s;
  }
}

__global__ __launch_bounds__(256) void assign_kernel(const int* __restrict__ tope,
    const float* __restrict__ topw, int* __restrict__ cursor,
    int* __restrict__ ptok, float* __restrict__ pw) {
  int t = blockIdx.x * 256 + threadIdx.x;
  if (t >= NT) return;
  #pragma unroll
  for (int k = 0; k < 2; k++) {
    int e = tope[t*2+k];
    int pos = atomicAdd(&cursor[e], 1);
    ptok[pos] = t;
    pw[pos]   = topw[t*2+k];
  }
}

// ---------------- fused up-projection (gate & up), SwiGLU epilogue ----------------
// C tile: 128 rows x 64 cols of BOTH matrices. BK=64. (round-3/9 proven)
template<bool ROUTED>
__global__ __launch_bounds__(256, 2) void gemm_up(
    const u16* __restrict__ X, const u16* __restrict__ Wg, const u16* __restrict__ Wu,
    const float* __restrict__ Bg, const float* __restrict__ Bu,
    u16* __restrict__ Hout,
    const int* __restrict__ offsets, const int* __restrict__ ptok,
    const float* __restrict__ pw, int Nfeat)
{
  int e = 0, seg = 0, cnt = NT;
  if (ROUTED) {
    e = blockIdx.z;
    seg = offsets[e];
    cnt = offsets[e+1] - seg;
  }
  const int G = ROUTED ? ((cnt + 127) >> 7) : (int)gridDim.y;
  int nt, mt;
  if (!xcd_map_band(G, nt, mt)) return;
  const int m0 = mt * 128;
  const int tid = threadIdx.x;
  const int wave = tid >> 6, lane = tid & 63;

  __shared__ u16 sA[128*64];
  __shared__ u16 sBg[64*64];
  __shared__ u16 sBu[64*64];
  char* sAc  = (char*)sA;
  char* sBgc = (char*)sBg;
  char* sBuc = (char*)sBu;

  const u16* aSrc[4];
  #pragma unroll
  for (int j = 0; j < 4; j++) {
    int c = j * 256 + tid;
    int row = c >> 3, gch = (c & 7) ^ (row & 7);
    int r = m0 + row;
    size_t srow;
    if (ROUTED) { r = (r < cnt) ? r : (cnt - 1); srow = (size_t)ptok[seg + r]; }
    else        { srow = (size_t)r; }
    aSrc[j] = X + srow * DIM + gch * 8;
  }
  const size_t wOff = ROUTED ? (size_t)e * Nfeat * DIM : 0;
  const u16 *bgSrc[2], *buSrc[2];
  #pragma unroll
  for (int j = 0; j < 2; j++) {
    int c = j * 256 + tid;
    int row = c >> 3, gch = (c & 7) ^ (row & 7);
    bgSrc[j] = Wg + wOff + (size_t)(nt * 64 + row) * DIM + gch * 8;
    buSrc[j] = Wu + wOff + (size_t)(nt * 64 + row) * DIM + gch * 8;
  }

  f32x4 accg[4][2], accu[4][2];
  #pragma unroll
  for (int m = 0; m < 4; m++)
    #pragma unroll
    for (int n = 0; n < 2; n++) { accg[m][n] = (f32x4){0,0,0,0}; accu[m][n] = (f32x4){0,0,0,0}; }

  const int wr = (wave >> 1) * 64;
  const int wc = (wave & 1) * 32;
  const int lr = lane & 15, kg = lane >> 4;
  int aOff[4], bOff[2];
  #pragma unroll
  for (int m = 0; m < 4; m++) { int row = wr + m*16 + lr; aOff[m] = row*128 + ((kg ^ (row & 7)) & 7) * 16; }
  #pragma unroll
  for (int n = 0; n < 2; n++) { int row = wc + n*16 + lr; bOff[n] = row*128 + ((kg ^ (row & 7)) & 7) * 16; }

  for (int k0 = 0; k0 < DIM; k0 += 64) {
    __syncthreads();
    #pragma unroll
    for (int j = 0; j < 4; j++) gload_lds16(aSrc[j] + k0, sAc + j*4096 + wave*1024);
    #pragma unroll
    for (int j = 0; j < 2; j++) {
      gload_lds16(bgSrc[j] + k0, sBgc + j*4096 + wave*1024);
      gload_lds16(buSrc[j] + k0, sBuc + j*4096 + wave*1024);
    }
    __syncthreads();
    bf16x8 af[4][2], bgf[2][2], buf2[2][2];
    #pragma unroll
    for (int m = 0; m < 4; m++) {
      af[m][0] = *(const bf16x8*)(sAc + aOff[m]);
      af[m][1] = *(const bf16x8*)(sAc + (aOff[m] ^ 64));
    }
    #pragma unroll
    for (int n = 0; n < 2; n++) {
      bgf[n][0]  = *(const bf16x8*)(sBgc + bOff[n]);
      bgf[n][1]  = *(const bf16x8*)(sBgc + (bOff[n] ^ 64));
      buf2[n][0] = *(const bf16x8*)(sBuc + bOff[n]);
      buf2[n][1] = *(const bf16x8*)(sBuc + (bOff[n] ^ 64));
    }
    #pragma unroll
    for (int kk = 0; kk < 2; kk++)
      #pragma unroll
      for (int m = 0; m < 4; m++)
        #pragma unroll
        for (int n = 0; n < 2; n++) {
          accg[m][n] = __builtin_amdgcn_mfma_f32_16x16x32_bf16(af[m][kk], bgf[n][kk],  accg[m][n], 0, 0, 0);
          accu[m][n] = __builtin_amdgcn_mfma_f32_16x16x32_bf16(af[m][kk], buf2[n][kk], accu[m][n], 0, 0, 0);
        }
  }

  const int col0 = nt * 64 + wc;
  #pragma unroll
  for (int m = 0; m < 4; m++) {
    #pragma unroll
    for (int n = 0; n < 2; n++) {
      #pragma unroll
      for (int i = 0; i < 4; i++) {
        int rl = wr + m*16 + (lane >> 4) * 4 + i;
        int gr = m0 + rl;
        if (ROUTED && gr >= cnt) continue;
        int col = col0 + n*16 + (lane & 15);
        float g = accg[m][n][i];
        float u = accu[m][n][i];
        float scale = 1.f;
        size_t orow;
        if (ROUTED) {
          int ai = seg + gr;
          scale = pw[ai];
          g += Bg[e * Nfeat + col];
          u += Bu[e * Nfeat + col];
          orow = (size_t)ai;
        } else {
          orow = (size_t)gr;
        }
        float s = g / (1.f + __expf(-g));
        Hout[orow * (size_t)Nfeat + col] = f2bf(s * u * scale);
      }
    }
  }
}

// ---------------- down-projection ----------------
// C tile: 128 x 128. BK=64. K = Kdim (NH or NHS). N = DIM. (round-3/9 proven)
template<bool ROUTED>
__global__ __launch_bounds__(256, 2) void gemm_down(
    const u16* __restrict__ Hin, const u16* __restrict__ W,
    const float* __restrict__ B2, float* __restrict__ Out,
    const int* __restrict__ offsets, const int* __restrict__ ptok,
    const float* __restrict__ pw, int Kdim)
{
  int e = 0, seg = 0, cnt = NT;
  if (ROUTED) {
    e = blockIdx.z;
    seg = offsets[e];
    cnt = offsets[e+1] - seg;
  }
  const int G = ROUTED ? ((cnt + 127) >> 7) : (int)gridDim.y;
  int nt, mt;
  if (!xcd_map_band(G, nt, mt)) return;
  const int m0 = mt * 128;
  const int tid = threadIdx.x;
  const int wave = tid >> 6, lane = tid & 63;

  __shared__ u16 sA[128*64];
  __shared__ u16 sB[128*64];
  char* sAc = (char*)sA;
  char* sBc = (char*)sB;

  const u16* aSrc[4]; const u16* bSrc[4];
  #pragma unroll
  for (int j = 0; j < 4; j++) {
    int c = j * 256 + tid;
    int row = c >> 3, gch = (c & 7) ^ (row & 7);
    int r = m0 + row;
    size_t arow;
    if (ROUTED) { r = (r < cnt) ? r : (cnt - 1); arow = (size_t)(seg + r); }
    else        { arow = (size_t)r; }
    aSrc[j] = Hin + arow * (size_t)Kdim + gch * 8;
    size_t brow = (size_t)(ROUTED ? e * DIM : 0) + nt * 128 + row;
    bSrc[j] = W + brow * (size_t)Kdim + gch * 8;
  }

  f32x4 acc[4][4];
  #pragma unroll
  for (int m = 0; m < 4; m++)
    #pragma unroll
    for (int n = 0; n < 4; n++) acc[m][n] = (f32x4){0,0,0,0};

  const int wr = (wave >> 1) * 64, wc = (wave & 1) * 64;
  const int lr = lane & 15, kg = lane >> 4;
  int aOff[4], bOff[4];
  #pragma unroll
  for (int m = 0; m < 4; m++) { int row = wr + m*16 + lr; aOff[m] = row*128 + ((kg ^ (row & 7)) & 7) * 16; }
  #pragma unroll
  for (int n = 0; n < 4; n++) { int row = wc + n*16 + lr; bOff[n] = row*128 + ((kg ^ (row & 7)) & 7) * 16; }

  for (int k0 = 0; k0 < Kdim; k0 += 64) {
    __syncthreads();
    #pragma unroll
    for (int j = 0; j < 4; j++) {
      gload_lds16(aSrc[j] + k0, sAc + j*4096 + wave*1024);
      gload_lds16(bSrc[j] + k0, sBc + j*4096 + wave*1024);
    }
    __syncthreads();
    bf16x8 af[4][2], bf[4][2];
    #pragma unroll
    for (int m = 0; m < 4; m++) {
      af[m][0] = *(const bf16x8*)(sAc + aOff[m]);
      af[m][1] = *(const bf16x8*)(sAc + (aOff[m] ^ 64));
    }
    #pragma unroll
    for (int n = 0; n < 4; n++) {
      bf[n][0] = *(const bf16x8*)(sBc + bOff[n]);
      bf[n][1] = *(const bf16x8*)(sBc + (bOff[n] ^ 64));
    }
    #pragma unroll
    for (int kk = 0; kk < 2; kk++)
      #pragma unroll
      for (int m = 0; m < 4; m++)
        #pragma unroll
        for (int n = 0; n < 4; n++)
          acc[m][n] = __builtin_amdgcn_mfma_f32_16x16x32_bf16(af[m][kk], bf[n][kk], acc[m][n], 0, 0, 0);
  }

  const int col0 = nt * 128 + wc;
  #pragma unroll
  for (int m = 0; m < 4; m++) {
    #pragma unroll
    for (int n = 0; n < 4; n++) {
      #pragma unroll
      for (int i = 0; i < 4; i++) {
        int rl = wr + m*16 + (lane >> 4) * 4 + i;
        int gr = m0 + rl;
        int col = col0 + n*16 + (lane & 15);
        float v = acc[m][n][i];
        if (ROUTED) {
          if (gr < cnt) {
            int ai = seg + gr;
            int token = ptok[ai];
            float w = pw[ai];
            atomicAdd(Out + (size_t)token * DIM + col, v + w * B2[e * DIM + col]);
          }
        } else {
          Out[(size_t)gr * DIM + col] = v;
        }
      }
    }
  }
}

// ---------------- launch ----------------
extern "C" void kernel_launch(void* const* d_in, const int* in_sizes, int n_in,
                              void* d_out, int out_size, void* d_ws, size_t ws_size,
                              hipStream_t stream) {
  (void)in_sizes; (void)n_in; (void)out_size; (void)ws_size;
  const float* x      = (const float*)d_in[0];
  const float* gate_w = (const float*)d_in[1];
  const float* gate_b = (const float*)d_in[2];
  const float* w1     = (const float*)d_in[3];
  const float* b1     = (const float*)d_in[4];
  const float* w3     = (const float*)d_in[5];
  const float* b3     = (const float*)d_in[6];
  const float* w2     = (const float*)d_in[7];
  const float* b2     = (const float*)d_in[8];
  const float* shg    = (const float*)d_in[9];
  const float* shu    = (const float*)d_in[10];
  const float* shd    = (const float*)d_in[11];
  float* out = (float*)d_out;

  char* ws = (char*)d_ws;
  size_t off = 0;
  auto alloc = [&](size_t bytes) -> void* {
    void* p = ws + off;
    off += (bytes + 255) & ~(size_t)255;
    return p;
  };
  u16* xb    = (u16*)alloc((size_t)NT * DIM * 2);
  u16* w1b   = (u16*)alloc((size_t)NEXP * NH * DIM * 2);
  u16* w3b   = (u16*)alloc((size_t)NEXP * NH * DIM * 2);
  u16* w2b   = (u16*)alloc((size_t)NEXP * DIM * NH * 2);
  u16* shgb  = (u16*)alloc((size_t)NHS * DIM * 2);
  u16* shub  = (u16*)alloc((size_t)NHS * DIM * 2);
  u16* shdb  = (u16*)alloc((size_t)DIM * NHS * 2);
  u16* hsh   = (u16*)alloc((size_t)NT * NHS * 2);
  u16* hr    = (u16*)alloc((size_t)NA * NH * 2);
  int*   tope    = (int*)alloc(NT * 2 * 4);
  float* topw    = (float*)alloc(NT * 2 * 4);
  int*   ptok    = (int*)alloc(NA * 4);
  float* pw      = (float*)alloc(NA * 4);
  int*   counts  = (int*)alloc(64);
  int*   offsets = (int*)alloc(64);
  int*   cursor  = (int*)alloc(64);

  auto cvt = [&](const float* s, u16* d, size_t n) {
    int n8 = (int)(n / 8);
    convert_kernel<<<(n8 + 255) / 256, 256, 0, stream>>>(s, d, n8);
  };
  cvt(w1,  w1b,  (size_t)NEXP * NH * DIM);
  cvt(w3,  w3b,  (size_t)NEXP * NH * DIM);
  cvt(w2,  w2b,  (size_t)NEXP * DIM * NH);
  cvt(shg, shgb, (size_t)NHS * DIM);
  cvt(shu, shub, (size_t)NHS * DIM);
  cvt(shd, shdb, (size_t)DIM * NHS);

  zero_counts<<<1, 64, 0, stream>>>(counts);
  router_kernel<<<NT, 64, 0, stream>>>(x, gate_w, gate_b, xb, tope, topw, counts);
  scan_kernel<<<1, 1, 0, stream>>>(counts, offsets, cursor);
  assign_kernel<<<NT / 256, 256, 0, stream>>>(tope, topw, cursor, ptok, pw);

  // shared expert: up (fused SwiGLU) then down (plain store initializes out)
  gemm_up<false><<<dim3(NHS / 64, NT / 128, 1), 256, 0, stream>>>(
      xb, shgb, shub, nullptr, nullptr, hsh, nullptr, nullptr, nullptr, NHS);
  // routed experts: up (fused SwiGLU * routing weight)
  gemm_up<true><<<dim3(NH / 64, NT / 128, NEXP), 256, 0, stream>>>(
      xb, w1b, w3b, b1, b3, hr, offsets, ptok, pw, NH);
  // shared down writes out, then routed down atomically accumulates
  gemm_down<false><<<dim3(DIM / 128, NT / 128, 1), 256, 0, stream>>>(
      hsh, shdb, nullptr, out, nullptr, nullptr, nullptr, NHS);
  gemm_down<true><<<dim3(DIM / 128, NT / 128, NEXP), 256, 0, stream>>>(
      hr, w2b, b2, out, offsets, ptok, pw, NH);
}